// Round 11
// baseline (1870.656 us; speedup 1.0000x reference)
//
#include <hip/hip_runtime.h>
#include <hip/hip_bf16.h>

#define N_NODES 100000
#define N_EDGES 800000
#define EPS 1e-5f
#define NBANK 32
#define HB_BLOCKS 256
#define HB_PER 3125          // 256 * 3125 = 800000 exactly
#define CS_GPB 64            // cscatter blocks per coarse bucket
#define BUCKET_N 12500       // 8 * 12500 = 100000 exactly
#define MROW 68              // LDS mean row stride in dwords (64 + 4 pad)
#define AROW 136             // LDS fp32 accum row stride in floats (128 + 8 pad)

typedef __attribute__((ext_vector_type(8))) short short8;
typedef __attribute__((ext_vector_type(4))) float floatx4;

__device__ __forceinline__ unsigned short f2b(float f) {
    unsigned int u = __float_as_uint(f);
    u = (u + 0x7fffu + ((u >> 16) & 1u)) >> 16;   // round-to-nearest-even
    return (unsigned short)u;
}
__device__ __forceinline__ float blo(unsigned int u) { return __uint_as_float(u << 16); }
__device__ __forceinline__ float bhi(unsigned int u) { return __uint_as_float(u & 0xffff0000u); }

// ---------------- elementwise convert fp32 -> bf16 (x input) ----------------
__global__ void cvt_f32_bf16(const float* __restrict__ x, unsigned short* __restrict__ o, int n4) {
    int i = blockIdx.x * blockDim.x + threadIdx.x;
    if (i >= n4) return;
    float4 v = ((const float4*)x)[i];
    ushort4 r;
    r.x = f2b(v.x); r.y = f2b(v.y); r.z = f2b(v.z); r.w = f2b(v.w);
    ((ushort4*)o)[i] = r;
}

// ---------------- pack [Wl;Wr] (K=256 x Hreal) into MFMA B-fragment order ----
__global__ void pack_w(const float* __restrict__ Wl, const float* __restrict__ Wr,
                       unsigned short* __restrict__ out, int Hreal, int NCT) {
    int tid = blockIdx.x * blockDim.x + threadIdx.x;
    int total = NCT * 8 * 64 * 8;
    if (tid >= total) return;
    int i = tid & 7;
    int lane = (tid >> 3) & 63;
    int q = tid >> 9;
    int c = q % NCT;
    int t = q / NCT;
    int k = t * 32 + (lane >> 4) * 8 + i;
    int n = c * 16 + (lane & 15);
    float v = 0.f;
    if (n < Hreal) v = (k < 128) ? Wl[k * Hreal + n] : Wr[(k - 128) * Hreal + n];
    out[tid] = f2b(v);
}

// ---------------- CSR build: two-level counting sort -------------------------
__global__ void __launch_bounds__(256) hist_k(const int* __restrict__ dst,
                                              unsigned int* __restrict__ cnt,
                                              unsigned int* __restrict__ bhist) {
    __shared__ unsigned int lh[8];
    if (threadIdx.x < 8) lh[threadIdx.x] = 0;
    __syncthreads();
    int start = blockIdx.x * HB_PER;
    for (int i = threadIdx.x; i < HB_PER; i += 256) {
        int d = dst[start + i];
        atomicAdd(&cnt[d], 1u);
        atomicAdd(&lh[(unsigned int)d / BUCKET_N], 1u);
    }
    __syncthreads();
    if (threadIdx.x < 8) bhist[threadIdx.x * HB_BLOCKS + blockIdx.x] = lh[threadIdx.x];
}

__global__ void bscan(unsigned int* __restrict__ A) {
    __shared__ unsigned int part[256];
    int t = threadIdx.x;
    unsigned int v[8];
    unsigned int s = 0;
#pragma unroll
    for (int i = 0; i < 8; i++) { v[i] = A[t * 8 + i]; s += v[i]; }
    part[t] = s; __syncthreads();
    for (int off = 1; off < 256; off <<= 1) {
        unsigned int add = (t >= off) ? part[t - off] : 0u;
        __syncthreads();
        part[t] += add;
        __syncthreads();
    }
    unsigned int base = part[t] - s;  // exclusive
#pragma unroll
    for (int i = 0; i < 8; i++) { unsigned int old = v[i]; A[t * 8 + i] = base; base += old; }
}

__global__ void __launch_bounds__(256) bscatter(const int* __restrict__ src,
                                                const int* __restrict__ dst,
                                                const unsigned int* __restrict__ boffs,
                                                unsigned int* __restrict__ ebuf) {
    __shared__ unsigned int cur[8];
    if (threadIdx.x < 8) cur[threadIdx.x] = boffs[threadIdx.x * HB_BLOCKS + blockIdx.x];
    __syncthreads();
    int start = blockIdx.x * HB_PER;
    for (int i = threadIdx.x; i < HB_PER; i += 256) {
        int d = dst[start + i];
        int s = src[start + i];
        unsigned int b = (unsigned int)d / BUCKET_N;
        unsigned int dl = (unsigned int)d - b * BUCKET_N;
        unsigned int pos = atomicAdd(&cur[b], 1u);
        ebuf[pos] = (unsigned int)s | (dl << 17);
    }
}

// fine scatter; packs (dst & 15) into bits 27..30 so the fused gemm's
// edge-parallel gather can resolve each edge's block-local row directly.
__global__ void __launch_bounds__(256) cscatter(const unsigned int* __restrict__ ebuf,
                                                const unsigned int* __restrict__ rowptr,
                                                unsigned int* __restrict__ cursor,
                                                unsigned int* __restrict__ srclist) {
    int g = blockIdx.x & 7;
    int gblk = blockIdx.x >> 3;
    unsigned int estart = rowptr[g * BUCKET_N];
    unsigned int eend = (g == 7) ? N_EDGES : rowptr[(g + 1) * BUCKET_N];
    unsigned int nume = eend - estart;
    unsigned int per = (nume + CS_GPB - 1) / CS_GPB;
    unsigned int s0 = estart + gblk * per;
    unsigned int s1 = s0 + per; if (s1 > eend) s1 = eend;
    unsigned int nodebase = g * BUCKET_N;
    for (unsigned int i = s0 + threadIdx.x; i < s1; i += 256) {
        unsigned int p = ebuf[i];
        unsigned int s = p & 0x1FFFFu;
        unsigned int node = nodebase + (p >> 17);
        unsigned int pos = atomicAdd(&cursor[node], 1u);
        srclist[pos] = s | ((node & 15u) << 27);
    }
}

__global__ void scan1(const unsigned int* __restrict__ cnt, unsigned int* __restrict__ rowptr,
                      unsigned int* __restrict__ bsum) {
    __shared__ unsigned int sh[256];
    int t = threadIdx.x;
    int i = blockIdx.x * 256 + t;
    unsigned int v = (i < N_NODES) ? cnt[i] : 0u;
    sh[t] = v; __syncthreads();
    for (int off = 1; off < 256; off <<= 1) {
        unsigned int add = (t >= off) ? sh[t - off] : 0u;
        __syncthreads();
        sh[t] += add;
        __syncthreads();
    }
    if (i < N_NODES) rowptr[i] = sh[t] - v;  // exclusive within block
    if (t == 255) bsum[blockIdx.x] = sh[255];
}

__global__ void scan2(const unsigned int* __restrict__ bsum, unsigned int* __restrict__ boff, int nb) {
    __shared__ unsigned int sh[512];
    int t = threadIdx.x;
    unsigned int v = (t < nb) ? bsum[t] : 0u;
    sh[t] = v; __syncthreads();
    for (int off = 1; off < 512; off <<= 1) {
        unsigned int add = (t >= off) ? sh[t - off] : 0u;
        __syncthreads();
        sh[t] += add;
        __syncthreads();
    }
    if (t < nb) boff[t] = sh[t] - v;
}

__global__ void scan3(unsigned int* __restrict__ rowptr, const unsigned int* __restrict__ boff,
                      unsigned int* __restrict__ cursor) {
    int i = blockIdx.x * 256 + threadIdx.x;
    if (i < N_NODES) {
        unsigned int r = rowptr[i] + boff[blockIdx.x];
        rowptr[i] = r;
        cursor[i] = r;
    }
    if (i == N_NODES) rowptr[N_NODES] = N_EDGES;
}

// ---------------- phase-1: edge-parallel gather into fp32 LDS accum ----------
// (R10 post-mortem: per-node groups -> wave runs max(ceil(deg/4)) iters over 4
//  Poisson(8) degrees ~ 2x issue waste. Now: 16 groups each take a contiguous
//  1/16 slice of the block's edge range; ds_add f32 atomics into [dl][j*16+l]
//  lane-interleaved accum; exact load balance, no divergence.)
__device__ __forceinline__ void agg_edges(const unsigned short* __restrict__ hb,
                                          const unsigned int* __restrict__ srclist,
                                          float* __restrict__ accum,
                                          unsigned int e0, unsigned int e1,
                                          int gid, int l) {
    const uint4* hp = (const uint4*)hb;
    unsigned int cnt = e1 - e0;
    unsigned int per = (cnt + 15) >> 4;
    unsigned int gs = e0 + gid * per;
    unsigned int ge = gs + per; if (ge > e1) ge = e1;
    if (gs >= e1) return;
    unsigned int p = gs;
    for (; p + 4 <= ge; p += 4) {
        unsigned int k0 = srclist[p];
        unsigned int k1 = srclist[p + 1];
        unsigned int k2 = srclist[p + 2];
        unsigned int k3 = srclist[p + 3];
        uint4 u0 = hp[(size_t)(k0 & 0x1FFFFu) * 16 + l];
        uint4 u1 = hp[(size_t)(k1 & 0x1FFFFu) * 16 + l];
        uint4 u2 = hp[(size_t)(k2 & 0x1FFFFu) * 16 + l];
        uint4 u3 = hp[(size_t)(k3 & 0x1FFFFu) * 16 + l];
        float* r0 = &accum[(k0 >> 27) * AROW + l];
        float* r1 = &accum[(k1 >> 27) * AROW + l];
        float* r2 = &accum[(k2 >> 27) * AROW + l];
        float* r3 = &accum[(k3 >> 27) * AROW + l];
        atomicAdd(&r0[0], blo(u0.x));  atomicAdd(&r0[16], bhi(u0.x));
        atomicAdd(&r0[32], blo(u0.y)); atomicAdd(&r0[48], bhi(u0.y));
        atomicAdd(&r0[64], blo(u0.z)); atomicAdd(&r0[80], bhi(u0.z));
        atomicAdd(&r0[96], blo(u0.w)); atomicAdd(&r0[112], bhi(u0.w));
        atomicAdd(&r1[0], blo(u1.x));  atomicAdd(&r1[16], bhi(u1.x));
        atomicAdd(&r1[32], blo(u1.y)); atomicAdd(&r1[48], bhi(u1.y));
        atomicAdd(&r1[64], blo(u1.z)); atomicAdd(&r1[80], bhi(u1.z));
        atomicAdd(&r1[96], blo(u1.w)); atomicAdd(&r1[112], bhi(u1.w));
        atomicAdd(&r2[0], blo(u2.x));  atomicAdd(&r2[16], bhi(u2.x));
        atomicAdd(&r2[32], blo(u2.y)); atomicAdd(&r2[48], bhi(u2.y));
        atomicAdd(&r2[64], blo(u2.z)); atomicAdd(&r2[80], bhi(u2.z));
        atomicAdd(&r2[96], blo(u2.w)); atomicAdd(&r2[112], bhi(u2.w));
        atomicAdd(&r3[0], blo(u3.x));  atomicAdd(&r3[16], bhi(u3.x));
        atomicAdd(&r3[32], blo(u3.y)); atomicAdd(&r3[48], bhi(u3.y));
        atomicAdd(&r3[64], blo(u3.z)); atomicAdd(&r3[80], bhi(u3.z));
        atomicAdd(&r3[96], blo(u3.w)); atomicAdd(&r3[112], bhi(u3.w));
    }
    for (; p < ge; ++p) {
        unsigned int k0 = srclist[p];
        uint4 u0 = hp[(size_t)(k0 & 0x1FFFFu) * 16 + l];
        float* r0 = &accum[(k0 >> 27) * AROW + l];
        atomicAdd(&r0[0], blo(u0.x));  atomicAdd(&r0[16], bhi(u0.x));
        atomicAdd(&r0[32], blo(u0.y)); atomicAdd(&r0[48], bhi(u0.y));
        atomicAdd(&r0[64], blo(u0.z)); atomicAdd(&r0[80], bhi(u0.z));
        atomicAdd(&r0[96], blo(u0.w)); atomicAdd(&r0[112], bhi(u0.w));
    }
}

// scale by 1/deg and pack fp32 accum -> bf16 smean. thread <-> (node nl, lane l)
__device__ __forceinline__ void agg_finish(const float* __restrict__ accum,
                                           const unsigned int* __restrict__ rowptr,
                                           unsigned int* __restrict__ smean,
                                           int blockrow) {
    int nl = threadIdx.x >> 4;
    int l = threadIdx.x & 15;
    int node = blockrow + nl;
    unsigned int deg = rowptr[node + 1] - rowptr[node];
    float r = 1.0f / (float)(deg > 1u ? deg : 1u);
    const float* a = &accum[nl * AROW + l];
    float f0 = a[0] * r,  f1 = a[16] * r, f2 = a[32] * r,  f3 = a[48] * r;
    float f4 = a[64] * r, f5 = a[80] * r, f6 = a[96] * r,  f7 = a[112] * r;
    uint4 o;
    o.x = (unsigned int)f2b(f0) | ((unsigned int)f2b(f1) << 16);
    o.y = (unsigned int)f2b(f2) | ((unsigned int)f2b(f3) << 16);
    o.z = (unsigned int)f2b(f4) | ((unsigned int)f2b(f5) << 16);
    o.w = (unsigned int)f2b(f6) | ((unsigned int)f2b(f7) << 16);
    *(uint4*)&smean[nl * MROW + l * 4] = o;
}

// ---------------- fused agg + GEMM L0/L1 + BN stats + bf16 C -----------------
// 16-row blocks, grid 6250 (= N/16). Phase 2: wave w handles cols [32w,32w+32).
__global__ void __launch_bounds__(256) gemm2f_k(const unsigned short* __restrict__ hb,
                                                const unsigned int* __restrict__ rowptr,
                                                const unsigned int* __restrict__ srclist,
                                                const unsigned short* __restrict__ Bp,
                                                unsigned short* __restrict__ outb,
                                                float* __restrict__ sums) {
    __shared__ float accum[16 * AROW];
    __shared__ unsigned int smean[16 * MROW];
    __shared__ float lds_s[128];
    __shared__ float lds_s2[128];
    int wave = threadIdx.x >> 6;
    int lane = threadIdx.x & 63;
    int quad = lane >> 4;
    int l15 = lane & 15;
    int gid = threadIdx.x >> 4;
    int blockrow = blockIdx.x * 16;

    if (threadIdx.x < 128) { lds_s[threadIdx.x] = 0.f; lds_s2[threadIdx.x] = 0.f; }
    for (int i = threadIdx.x; i < 16 * AROW; i += 256) accum[i] = 0.f;
    __syncthreads();

    unsigned int e0 = rowptr[blockrow];
    unsigned int e1 = rowptr[blockrow + 16];
    agg_edges(hb, srclist, accum, e0, e1, gid, l15);
    __syncthreads();
    agg_finish(accum, rowptr, smean, blockrow);
    __syncthreads();

    floatx4 acc[2];
    acc[0] = (floatx4){0.f, 0.f, 0.f, 0.f};
    acc[1] = (floatx4){0.f, 0.f, 0.f, 0.f};

    int r0 = blockrow + l15;   // always < N_NODES (exact division)

#pragma unroll
    for (int t = 0; t < 8; t++) {
        short8 a0;
        if (t < 4) {
            a0 = *(const short8*)&smean[l15 * MROW + t * 16 + quad * 4];
        } else {
            int koff = (t & 3) * 32 + quad * 8;
            a0 = *(const short8*)(hb + (size_t)r0 * 128 + koff);
        }
#pragma unroll
        for (int c = 0; c < 2; c++) {
            int cidx = wave * 2 + c;
            short8 bf = *(const short8*)(Bp + ((size_t)(t * 8 + cidx) * 64 + lane) * 8);
            acc[c] = __builtin_amdgcn_mfma_f32_16x16x32_bf16(a0, bf, acc[c], 0, 0, 0);
        }
    }

#pragma unroll
    for (int c = 0; c < 2; c++) {
        int col = wave * 32 + c * 16 + l15;
        float s = 0.f, s2 = 0.f;
#pragma unroll
        for (int r = 0; r < 4; r++) {
            int row = blockrow + quad * 4 + r;
            float v = acc[c][r];
            outb[(size_t)row * 128 + col] = f2b(v);
            s += v; s2 += v * v;
        }
        s += __shfl_xor(s, 16);  s += __shfl_xor(s, 32);
        s2 += __shfl_xor(s2, 16); s2 += __shfl_xor(s2, 32);
        if (quad == 0) {
            atomicAdd(&lds_s[col], s);
            atomicAdd(&lds_s2[col], s2);
        }
    }

    __syncthreads();
    if (threadIdx.x < 128) {
        int bank = blockIdx.x & (NBANK - 1);
        atomicAdd(&sums[bank * 256 + threadIdx.x], lds_s[threadIdx.x]);
        atomicAdd(&sums[bank * 256 + 128 + threadIdx.x], lds_s2[threadIdx.x]);
    }
}

// ---------------- fused agg + GEMM L2 (40 cols, bias, fp32 out) --------------
__global__ void __launch_bounds__(256) gemm3f_k(const unsigned short* __restrict__ hb,
                                                const unsigned int* __restrict__ rowptr,
                                                const unsigned int* __restrict__ srclist,
                                                const unsigned short* __restrict__ Bp,
                                                const float* __restrict__ bias,
                                                float* __restrict__ out) {
    __shared__ float accum[16 * AROW];
    __shared__ unsigned int smean[16 * MROW];
    int wave = threadIdx.x >> 6;
    int lane = threadIdx.x & 63;
    int quad = lane >> 4;
    int l15 = lane & 15;
    int gid = threadIdx.x >> 4;
    int blockrow = blockIdx.x * 16;

    for (int i = threadIdx.x; i < 16 * AROW; i += 256) accum[i] = 0.f;
    __syncthreads();
    unsigned int e0 = rowptr[blockrow];
    unsigned int e1 = rowptr[blockrow + 16];
    agg_edges(hb, srclist, accum, e0, e1, gid, l15);
    __syncthreads();
    agg_finish(accum, rowptr, smean, blockrow);
    __syncthreads();

    if (wave >= 3) return;

    floatx4 acc = (floatx4){0.f, 0.f, 0.f, 0.f};
    int r0 = blockrow + l15;

#pragma unroll
    for (int t = 0; t < 8; t++) {
        short8 a0;
        if (t < 4) {
            a0 = *(const short8*)&smean[l15 * MROW + t * 16 + quad * 4];
        } else {
            int koff = (t & 3) * 32 + quad * 8;
            a0 = *(const short8*)(hb + (size_t)r0 * 128 + koff);
        }
        short8 bf = *(const short8*)(Bp + ((size_t)(t * 3 + wave) * 64 + lane) * 8);
        acc = __builtin_amdgcn_mfma_f32_16x16x32_bf16(a0, bf, acc, 0, 0, 0);
    }

    int col = wave * 16 + l15;
    if (col < 40) {
#pragma unroll
        for (int r = 0; r < 4; r++) {
            int row = blockrow + quad * 4 + r;
            out[(size_t)row * 40 + col] = acc[r] + bias[col];
        }
    }
}

// ---------------- BN finalize (reduce 32 banks) ------------------------------
__global__ void bn_finalize(const float* __restrict__ sums, const float* __restrict__ g,
                            const float* __restrict__ be, float* __restrict__ sc,
                            float* __restrict__ sh) {
    __shared__ float lds[256];
    int t = threadIdx.x;
    float s = 0.f;
#pragma unroll 8
    for (int bk = 0; bk < NBANK; bk++) s += sums[bk * 256 + t];
    lds[t] = s;
    __syncthreads();
    if (t < 128) {
        float inv_n = 1.0f / (float)N_NODES;
        float mu = lds[t] * inv_n;
        float var = lds[128 + t] * inv_n - mu * mu;
        float sf = g[t] * rsqrtf(var + EPS);
        sc[t] = sf;
        sh[t] = be[t] - mu * sf;
    }
}

// ---------------- BN apply: bf16 in -> bf16 out, 8 elems/thread --------------
__global__ void bn_apply(const unsigned int* __restrict__ Cb, const float* __restrict__ sc,
                         const float* __restrict__ sh, unsigned short* __restrict__ ho) {
    int i = blockIdx.x * 256 + threadIdx.x;  // one uint4 = 8 bf16
    if (i >= N_NODES * 16) return;
    uint4 v = ((const uint4*)Cb)[i];
    int c0 = (i * 8) & 127;
    uint4 o;
    float e0 = fmaxf(0.f, blo(v.x) * sc[c0 + 0] + sh[c0 + 0]);
    float e1 = fmaxf(0.f, bhi(v.x) * sc[c0 + 1] + sh[c0 + 1]);
    float e2 = fmaxf(0.f, blo(v.y) * sc[c0 + 2] + sh[c0 + 2]);
    float e3 = fmaxf(0.f, bhi(v.y) * sc[c0 + 3] + sh[c0 + 3]);
    float e4 = fmaxf(0.f, blo(v.z) * sc[c0 + 4] + sh[c0 + 4]);
    float e5 = fmaxf(0.f, bhi(v.z) * sc[c0 + 5] + sh[c0 + 5]);
    float e6 = fmaxf(0.f, blo(v.w) * sc[c0 + 6] + sh[c0 + 6]);
    float e7 = fmaxf(0.f, bhi(v.w) * sc[c0 + 7] + sh[c0 + 7]);
    o.x = (unsigned int)f2b(e0) | ((unsigned int)f2b(e1) << 16);
    o.y = (unsigned int)f2b(e2) | ((unsigned int)f2b(e3) << 16);
    o.z = (unsigned int)f2b(e4) | ((unsigned int)f2b(e5) << 16);
    o.w = (unsigned int)f2b(e6) | ((unsigned int)f2b(e7) << 16);
    ((uint4*)ho)[i] = o;
}

// ---------------- host ----------------
extern "C" void kernel_launch(void* const* d_in, const int* in_sizes, int n_in,
                              void* d_out, int out_size, void* d_ws, size_t ws_size,
                              hipStream_t stream) {
    const float* x   = (const float*)d_in[0];
    const int* ei    = (const int*)d_in[1];     // [2, E] int32: row 0 = src, row 1 = dst
    const float* Wl0 = (const float*)d_in[2];
    const float* Wr0 = (const float*)d_in[3];
    const float* Wl1 = (const float*)d_in[4];
    const float* Wr1 = (const float*)d_in[5];
    const float* Wl2 = (const float*)d_in[6];
    const float* Wr2 = (const float*)d_in[7];
    const float* b2  = (const float*)d_in[8];
    const float* g0  = (const float*)d_in[9];
    const float* be0 = (const float*)d_in[10];
    const float* g1  = (const float*)d_in[11];
    const float* be1 = (const float*)d_in[12];

    char* ws = (char*)d_ws;
    size_t off = 0;
    auto alloc = [&](size_t bytes) -> void* {
        void* p = ws + off;
        off += (bytes + 4095) & ~(size_t)4095;
        return p;
    };

    const size_t NB16 = (size_t)N_NODES * 128 * 2;  // 25.6 MB bf16 feature buffer
    unsigned short* xb   = (unsigned short*)alloc(NB16);   // x in bf16; reused as h2
    unsigned short* h1   = (unsigned short*)alloc(NB16);
    unsigned short* C    = (unsigned short*)alloc(NB16);   // pre-BN bf16
    unsigned int* cnt    = (unsigned int*)alloc((size_t)N_NODES * 4);
    unsigned int* rowptr = (unsigned int*)alloc((size_t)(N_NODES + 1) * 4);
    unsigned int* cursor = (unsigned int*)alloc((size_t)N_NODES * 4);
    unsigned int* srclist= (unsigned int*)alloc((size_t)N_EDGES * 4);
    unsigned int* ebuf   = (unsigned int*)alloc((size_t)N_EDGES * 4);
    unsigned int* bhist  = (unsigned int*)alloc(8 * HB_BLOCKS * 4);
    unsigned int* bsum   = (unsigned int*)alloc(512 * 4);
    unsigned int* boff   = (unsigned int*)alloc(512 * 4);
    float* sums0         = (float*)alloc(NBANK * 256 * 4);   // contiguous with sums1
    float* sums1         = (float*)alloc(NBANK * 256 * 4);
    float* sc            = (float*)alloc(128 * 4);
    float* sh            = (float*)alloc(128 * 4);
    unsigned short* W0p  = (unsigned short*)alloc(8 * 8 * 64 * 8 * 2);
    unsigned short* W1p  = (unsigned short*)alloc(8 * 8 * 64 * 8 * 2);
    unsigned short* W2p  = (unsigned short*)alloc(3 * 8 * 64 * 8 * 2);
    unsigned short* h2   = xb;  // alias: xb dead after layer-0 GEMM

    const int* srcp = ei;
    const int* dstp = ei + N_EDGES;

    // ---- prep (both BN sums buffers zeroed up front; none mid-pipeline) ----
    hipMemsetAsync(cnt, 0, (size_t)N_NODES * 4, stream);
    hipMemsetAsync(sums0, 0, (size_t)2 * NBANK * 256 * 4, stream);  // sums0+sums1
    cvt_f32_bf16<<<12500, 256, 0, stream>>>(x, xb, N_NODES * 32);
    pack_w<<<(8 * 4096 + 255) / 256, 256, 0, stream>>>(Wl0, Wr0, W0p, 128, 8);
    pack_w<<<(8 * 4096 + 255) / 256, 256, 0, stream>>>(Wl1, Wr1, W1p, 128, 8);
    pack_w<<<(3 * 4096 + 255) / 256, 256, 0, stream>>>(Wl2, Wr2, W2p, 40, 3);

    // ---- CSR (two-level counting sort) ----
    hist_k<<<HB_BLOCKS, 256, 0, stream>>>(dstp, cnt, bhist);
    scan1<<<391, 256, 0, stream>>>(cnt, rowptr, bsum);
    scan2<<<1, 512, 0, stream>>>(bsum, boff, 391);
    scan3<<<391, 256, 0, stream>>>(rowptr, boff, cursor);
    bscan<<<1, 256, 0, stream>>>(bhist);
    bscatter<<<HB_BLOCKS, 256, 0, stream>>>(srcp, dstp, bhist, ebuf);
    cscatter<<<8 * CS_GPB, 256, 0, stream>>>(ebuf, rowptr, cursor, srclist);

    // ---- layer 0 (fused agg+gemm, 16-row blocks, edge-parallel gather) ----
    gemm2f_k<<<6250, 256, 0, stream>>>(xb, rowptr, srclist, W0p, C, sums0);
    bn_finalize<<<1, 256, 0, stream>>>(sums0, g0, be0, sc, sh);
    bn_apply<<<6250, 256, 0, stream>>>((const unsigned int*)C, sc, sh, h1);

    // ---- layer 1 ----
    gemm2f_k<<<6250, 256, 0, stream>>>(h1, rowptr, srclist, W1p, C, sums1);
    bn_finalize<<<1, 256, 0, stream>>>(sums1, g1, be1, sc, sh);
    bn_apply<<<6250, 256, 0, stream>>>((const unsigned int*)C, sc, sh, h2);

    // ---- layer 2 (writes d_out, fp32 [N,40]) ----
    gemm3f_k<<<6250, 256, 0, stream>>>(h2, rowptr, srclist, W2p, b2, (float*)d_out);

    (void)in_sizes; (void)n_in; (void)out_size; (void)ws_size;
}